// Round 1
// baseline (508.885 us; speedup 1.0000x reference)
//
#include <hip/hip_runtime.h>

#define N_NODES 20000
#define N_EDGES 400000
#define NODE_DIM 256
#define HIDDEN 256
#define OUT_DIM 128

// ---------------- Kernel 1: C[n, 0:256] = x @ W_src ; C[n, 256:512] = x @ W_dst
// classic fp32 tiled GEMM: BM=64 BN=64 BK=16, 256 threads, 4x4 micro-tile.
// Also zeroes the partial-sum buffer (block (0,0)) so kernel 2 can atomicAdd.
__global__ __launch_bounds__(256) void proj_gemm(
    const float* __restrict__ x, const float* __restrict__ We,
    float* __restrict__ C, float* __restrict__ partial) {
  if (blockIdx.x == 0 && blockIdx.y == 0) {
    for (int i = threadIdx.x; i < 4 * HIDDEN; i += 256) partial[i] = 0.0f;
  }
  __shared__ float As[16][65];  // [k][m], +1 pad breaks write conflicts
  __shared__ float Bs[16][65];  // [k][n]
  const int tid = threadIdx.x;
  const int row0 = blockIdx.x * 64;
  const int col0 = blockIdx.y * 64;            // 0..511 across both halves
  const int brow_off = (col0 >= 256) ? 256 : 0; // W_dst rows start at 256
  const int bcol0 = col0 & 255;
  const int tm = tid >> 4;  // 0..15
  const int tn = tid & 15;  // 0..15
  const int ar = tid >> 4;  // A-tile row group
  const int ac = tid & 15;  // A-tile k
  const int br = tid >> 6;  // B-tile k group
  const int bc = tid & 63;  // B-tile col
  float acc[4][4] = {{0.f}};
  for (int k0 = 0; k0 < NODE_DIM; k0 += 16) {
#pragma unroll
    for (int i = 0; i < 4; ++i) {
      int r = row0 + ar + 16 * i;
      As[ac][ar + 16 * i] = (r < N_NODES) ? x[(size_t)r * NODE_DIM + k0 + ac] : 0.0f;
    }
#pragma unroll
    for (int i = 0; i < 4; ++i) {
      int kk = k0 + br + 4 * i;
      Bs[br + 4 * i][bc] = We[(size_t)(brow_off + kk) * HIDDEN + bcol0 + bc];
    }
    __syncthreads();
#pragma unroll
    for (int k = 0; k < 16; ++k) {
      float a[4], bm[4];
#pragma unroll
      for (int i = 0; i < 4; ++i) a[i] = As[k][tm * 4 + i];
#pragma unroll
      for (int j = 0; j < 4; ++j) bm[j] = Bs[k][tn * 4 + j];
#pragma unroll
      for (int i = 0; i < 4; ++i)
#pragma unroll
        for (int j = 0; j < 4; ++j) acc[i][j] = fmaf(a[i], bm[j], acc[i][j]);
    }
    __syncthreads();
  }
#pragma unroll
  for (int i = 0; i < 4; ++i) {
    int r = row0 + tm * 4 + i;
    if (r < N_NODES) {
#pragma unroll
      for (int j = 0; j < 4; ++j)
        C[(size_t)r * 512 + col0 + tn * 4 + j] = acc[i][j];
    }
  }
}

// ---------------- Kernel 2: fused gather + attr-GEMM + relu + mean-reduction.
// Thread h (0..255) owns hidden column h. W_attr column in 16 registers.
// Edges processed in groups of 8; attrs staged through LDS (coalesced),
// then broadcast-read. acc[b] accumulated locally, one atomicAdd per (b,h).
__global__ __launch_bounds__(256) void edge_reduce(
    const float* __restrict__ C, const int* __restrict__ ei,
    const float* __restrict__ attrs, const float* __restrict__ We,
    const float* __restrict__ be, float* __restrict__ partial) {
  const int h = threadIdx.x;
  float Wk[16];
#pragma unroll
  for (int k = 0; k < 16; ++k) Wk[k] = We[(size_t)(2 * NODE_DIM + k) * HIDDEN + h];
  const float bias = be[h];
  float acc[4] = {0.f, 0.f, 0.f, 0.f};
  __shared__ float a_lds[512];  // [b][j][k] = b*128 + j*16 + k
  __shared__ int idx_lds[16];   // [which][j]
  const int ngroups = N_EDGES / 8;
  for (int g = blockIdx.x; g < ngroups; g += gridDim.x) {
    const int e0 = g * 8;
    __syncthreads();  // protect previous iteration's LDS reads
#pragma unroll
    for (int i = 0; i < 2; ++i) {
      int f = h + 256 * i;
      int b = f >> 7, rem = f & 127, j = rem >> 4, k = rem & 15;
      a_lds[f] = attrs[((size_t)b * N_EDGES + e0 + j) * 16 + k];
    }
    if (h < 16) idx_lds[h] = ei[(h >> 3) * N_EDGES + e0 + (h & 7)];
    __syncthreads();
#pragma unroll
    for (int j = 0; j < 8; ++j) {
      const int ns = idx_lds[j];
      const int nd = idx_lds[8 + j];
      const float bh = C[(size_t)ns * 512 + h] + C[(size_t)nd * 512 + 256 + h] + bias;
#pragma unroll
      for (int b = 0; b < 4; ++b) {
        float t = 0.f;
#pragma unroll
        for (int k = 0; k < 16; ++k)
          t = fmaf(a_lds[b * 128 + j * 16 + k], Wk[k], t);
        acc[b] += fmaxf(bh + t, 0.f);
      }
    }
  }
#pragma unroll
  for (int b = 0; b < 4; ++b) atomicAdd(&partial[b * HIDDEN + h], acc[b]);
}

// ---------------- Kernel 3: out[b,o] = (S[b,:]/E) @ W_graph + b_graph
__global__ __launch_bounds__(512) void graph_out(
    const float* __restrict__ partial, const float* __restrict__ Wg,
    const float* __restrict__ bg, float* __restrict__ out) {
  const int t = threadIdx.x;  // 0..511
  const int b = t >> 7, o = t & 127;
  float s = 0.f;
  for (int hh = 0; hh < HIDDEN; ++hh)
    s = fmaf(partial[b * HIDDEN + hh], Wg[hh * OUT_DIM + o], s);
  out[t] = s * (1.0f / (float)N_EDGES) + bg[o];
}

extern "C" void kernel_launch(void* const* d_in, const int* in_sizes, int n_in,
                              void* d_out, int out_size, void* d_ws, size_t ws_size,
                              hipStream_t stream) {
  const float* x  = (const float*)d_in[0];
  const int*   ei = (const int*)d_in[1];
  const float* ea = (const float*)d_in[2];
  const float* We = (const float*)d_in[3];
  const float* be = (const float*)d_in[4];
  const float* Wg = (const float*)d_in[5];
  const float* bg = (const float*)d_in[6];
  float* out = (float*)d_out;

  float* C = (float*)d_ws;                         // 20000*512 floats = 40.96 MB
  float* partial = C + (size_t)N_NODES * 512;      // 4*256 floats

  dim3 g1((N_NODES + 63) / 64, 8);
  proj_gemm<<<g1, 256, 0, stream>>>(x, We, C, partial);
  edge_reduce<<<2048, 256, 0, stream>>>(C, ei, ea, We, be, partial);
  graph_out<<<1, 512, 0, stream>>>(partial, Wg, bg, out);
}

// Round 3
// 349.540 us; speedup vs baseline: 1.4559x; 1.4559x over previous
//
#include <hip/hip_runtime.h>

#define N_NODES 20000
#define N_EDGES 400000
#define NODE_DIM 256
#define HIDDEN 256
#define OUT_DIM 128

typedef __attribute__((ext_vector_type(8))) short short8;
typedef __attribute__((ext_vector_type(4))) float f32x4;

__device__ inline short f2bf(float f) {
  union { float f; unsigned u; } v; v.f = f;
  unsigned r = (v.u + 0x7FFFu + ((v.u >> 16) & 1u)) >> 16;
  return (short)r;
}

// ---------------- Kernel 1: C[n, 0:256] = x @ W_src ; C[n, 256:512] = x @ W_dst
// fp32 tiled GEMM: BM=64 BN=128 BK=16, 256 threads, 4x8 micro-tile.
// Also zeroes the partial-sum buffer (block (0,0)).
__global__ __launch_bounds__(256) void proj_gemm(
    const float* __restrict__ x, const float* __restrict__ We,
    float* __restrict__ C, float* __restrict__ partial) {
  if (blockIdx.x == 0 && blockIdx.y == 0) {
    for (int i = threadIdx.x; i < 4 * HIDDEN; i += 256) partial[i] = 0.0f;
  }
  __shared__ float As[16][68];   // [k][m], pad keeps float4 alignment
  __shared__ float Bs[16][132];  // [k][n]
  const int tid = threadIdx.x;
  const int row0 = blockIdx.x * 64;
  const int col0 = blockIdx.y * 128;            // 0..511 across both halves
  const int brow_off = (col0 >= 256) ? 256 : 0; // W_dst rows start at 256
  const int bcol0 = col0 & 255;
  const int tm = tid >> 4;   // 0..15 -> rows tm*4..+3
  const int tn = tid & 15;   // 0..15 -> cols tn*8..+7
  const int ar = tid >> 4;   // A row group
  const int ac = tid & 15;   // A k
  const int bcol = tid & 127;
  const int bk0 = tid >> 7;  // 0..1
  float acc[4][8];
#pragma unroll
  for (int i = 0; i < 4; ++i)
#pragma unroll
    for (int j = 0; j < 8; ++j) acc[i][j] = 0.f;

  for (int k0 = 0; k0 < NODE_DIM; k0 += 16) {
#pragma unroll
    for (int i = 0; i < 4; ++i) {
      int r = row0 + ar + 16 * i;
      As[ac][ar + 16 * i] = (r < N_NODES) ? x[(size_t)r * NODE_DIM + k0 + ac] : 0.0f;
    }
#pragma unroll
    for (int i = 0; i < 8; ++i) {
      int kk = bk0 + 2 * i;
      Bs[kk][bcol] = We[(size_t)(brow_off + k0 + kk) * HIDDEN + bcol0 + bcol];
    }
    __syncthreads();
#pragma unroll
    for (int k = 0; k < 16; ++k) {
      const float4 a = *(const float4*)&As[k][tm * 4];
      const float4 b0 = *(const float4*)&Bs[k][tn * 8];
      const float4 b1 = *(const float4*)&Bs[k][tn * 8 + 4];
      const float av[4] = {a.x, a.y, a.z, a.w};
      const float bv[8] = {b0.x, b0.y, b0.z, b0.w, b1.x, b1.y, b1.z, b1.w};
#pragma unroll
      for (int i = 0; i < 4; ++i)
#pragma unroll
        for (int j = 0; j < 8; ++j) acc[i][j] = fmaf(av[i], bv[j], acc[i][j]);
    }
    __syncthreads();
  }
#pragma unroll
  for (int i = 0; i < 4; ++i) {
    int r = row0 + tm * 4 + i;
    if (r < N_NODES) {
      float4 s0 = {acc[i][0], acc[i][1], acc[i][2], acc[i][3]};
      float4 s1 = {acc[i][4], acc[i][5], acc[i][6], acc[i][7]};
      *(float4*)&C[(size_t)r * 512 + col0 + tn * 8] = s0;
      *(float4*)&C[(size_t)r * 512 + col0 + tn * 8 + 4] = s1;
    }
  }
}

// ---------------- Kernel 2: MFMA fused gather + attr-GEMM + relu + mean.
// Wave w owns h in [64w, 64w+64). 16 edges/group. A = attrs (bf16, K padded
// 16->32), B = W_attr columns (resident in 16 VGPRs). Base (src+dst proj)
// gathered in fp32 from C. Layouts per guide: A/B [m|n=lane&15][k=quad*8+j],
// C/D col=lane&15 row=quad*4+reg.
__global__ __launch_bounds__(256) void edge_mfma(
    const float* __restrict__ C, const int* __restrict__ ei,
    const float* __restrict__ attrs, const float* __restrict__ We,
    const float* __restrict__ be, float* __restrict__ partial) {
  const int tid = threadIdx.x;
  const int lane = tid & 63;
  const int wave = tid >> 6;
  const int q = lane >> 4;   // quad
  const int c = lane & 15;   // column-in-tile / A row
  const int hb = wave * 64;

  // B fragments: Bf[t][j] = W_attr[k=q*8+j][hb+t*16+c], zero-padded k>=16
  short8 Bf[4];
#pragma unroll
  for (int t = 0; t < 4; ++t) {
    short8 bf;
#pragma unroll
    for (int j = 0; j < 8; ++j) {
      int k = q * 8 + j;
      float w = (k < 16) ? We[(size_t)(512 + k) * HIDDEN + hb + t * 16 + c] : 0.0f;
      bf[j] = f2bf(w);
    }
    Bf[t] = bf;
  }
  float biasv[4];
#pragma unroll
  for (int t = 0; t < 4; ++t) biasv[t] = be[hb + t * 16 + c];

  float acc[4][4];  // [b][t]
#pragma unroll
  for (int b = 0; b < 4; ++b)
#pragma unroll
    for (int t = 0; t < 4; ++t) acc[b][t] = 0.f;

  const f32x4 zero4 = {0.f, 0.f, 0.f, 0.f};
  const int ngroups = N_EDGES / 16;
  for (int g = blockIdx.x; g < ngroups; g += gridDim.x) {
    const int e0 = g * 16;
    // edge indices for this quad's 4 rows
    const int4 ns4 = *(const int4*)&ei[e0 + q * 4];
    const int4 nd4 = *(const int4*)&ei[N_EDGES + e0 + q * 4];

    // A fragments: lane row m=c, k=q*8+j (real data only for q<2)
    short8 Af[4];
    if (q < 2) {
#pragma unroll
      for (int b = 0; b < 4; ++b) {
        const size_t base_off = ((size_t)b * N_EDGES + e0 + c) * 16 + q * 8;
        const float4 a0 = *(const float4*)&attrs[base_off];
        const float4 a1 = *(const float4*)&attrs[base_off + 4];
        short8 af;
        af[0] = f2bf(a0.x); af[1] = f2bf(a0.y); af[2] = f2bf(a0.z); af[3] = f2bf(a0.w);
        af[4] = f2bf(a1.x); af[5] = f2bf(a1.y); af[6] = f2bf(a1.z); af[7] = f2bf(a1.w);
        Af[b] = af;
      }
    } else {
#pragma unroll
      for (int b = 0; b < 4; ++b) {
        short8 af;
#pragma unroll
        for (int j = 0; j < 8; ++j) af[j] = 0;
        Af[b] = af;
      }
    }

    // base[t][r] = Csrc + Cdst + bias for (row=q*4+r, col=hb+t*16+c)
    float base[4][4];
#pragma unroll
    for (int t = 0; t < 4; ++t) {
      const int h = hb + t * 16 + c;
      base[t][0] = C[(size_t)ns4.x * 512 + h] + C[(size_t)nd4.x * 512 + 256 + h] + biasv[t];
      base[t][1] = C[(size_t)ns4.y * 512 + h] + C[(size_t)nd4.y * 512 + 256 + h] + biasv[t];
      base[t][2] = C[(size_t)ns4.z * 512 + h] + C[(size_t)nd4.z * 512 + 256 + h] + biasv[t];
      base[t][3] = C[(size_t)ns4.w * 512 + h] + C[(size_t)nd4.w * 512 + 256 + h] + biasv[t];
    }

#pragma unroll
    for (int b = 0; b < 4; ++b) {
      f32x4 S[4];
#pragma unroll
      for (int t = 0; t < 4; ++t)
        S[t] = __builtin_amdgcn_mfma_f32_16x16x32_bf16(Af[b], Bf[t], zero4, 0, 0, 0);
#pragma unroll
      for (int t = 0; t < 4; ++t) {
        acc[b][t] += fmaxf(S[t][0] + base[t][0], 0.f)
                   + fmaxf(S[t][1] + base[t][1], 0.f)
                   + fmaxf(S[t][2] + base[t][2], 0.f)
                   + fmaxf(S[t][3] + base[t][3], 0.f);
      }
    }
  }

  // reduce across quads (lanes c, c+16, c+32, c+48), then one atomic per (b,h)
#pragma unroll
  for (int b = 0; b < 4; ++b)
#pragma unroll
    for (int t = 0; t < 4; ++t) {
      float v = acc[b][t];
      v += __shfl_xor(v, 16, 64);
      v += __shfl_xor(v, 32, 64);
      if (q == 0) atomicAdd(&partial[b * HIDDEN + hb + t * 16 + c], v);
    }
}

// ---------------- Kernel 3: out[b,o] = (S[b,:]/E) @ W_graph + b_graph
__global__ __launch_bounds__(256) void graph_out(
    const float* __restrict__ partial, const float* __restrict__ Wg,
    const float* __restrict__ bg, float* __restrict__ out) {
  const int o = blockIdx.x;    // 0..127
  const int hh = threadIdx.x;  // 0..255
  const int lane = hh & 63, wave = hh >> 6;
  const float w = Wg[(size_t)hh * OUT_DIM + o];
  float v[4];
#pragma unroll
  for (int b = 0; b < 4; ++b) v[b] = partial[b * HIDDEN + hh] * w;
#pragma unroll
  for (int off = 32; off >= 1; off >>= 1)
#pragma unroll
    for (int b = 0; b < 4; ++b) v[b] += __shfl_down(v[b], off, 64);
  __shared__ float red[4][4];
  if (lane == 0)
#pragma unroll
    for (int b = 0; b < 4; ++b) red[wave][b] = v[b];
  __syncthreads();
  if (hh < 4) {
    float s = red[0][hh] + red[1][hh] + red[2][hh] + red[3][hh];
    out[hh * OUT_DIM + o] = s * (1.0f / (float)N_EDGES) + bg[o];
  }
}

extern "C" void kernel_launch(void* const* d_in, const int* in_sizes, int n_in,
                              void* d_out, int out_size, void* d_ws, size_t ws_size,
                              hipStream_t stream) {
  const float* x  = (const float*)d_in[0];
  const int*   ei = (const int*)d_in[1];
  const float* ea = (const float*)d_in[2];
  const float* We = (const float*)d_in[3];
  const float* be = (const float*)d_in[4];
  const float* Wg = (const float*)d_in[5];
  const float* bg = (const float*)d_in[6];
  float* out = (float*)d_out;

  float* C = (float*)d_ws;                     // 20000*512 floats = 40.96 MB
  float* partial = C + (size_t)N_NODES * 512;  // 4*256 floats

  dim3 g1((N_NODES + 63) / 64, 4);
  proj_gemm<<<g1, 256, 0, stream>>>(x, We, C, partial);
  edge_mfma<<<2048, 256, 0, stream>>>(C, ei, ea, We, be, partial);
  graph_out<<<128, 256, 0, stream>>>(partial, Wg, bg, out);
}

// Round 5
// 287.408 us; speedup vs baseline: 1.7706x; 1.2162x over previous
//
#include <hip/hip_runtime.h>

#define N_NODES 20000
#define N_EDGES 400000
#define NODE_DIM 256
#define HIDDEN 256
#define OUT_DIM 128
#define PROJ_BLOCKS 628  // 157 m-blocks * 4 n-blocks
#define CONV_BLOCKS 256

typedef __attribute__((ext_vector_type(8))) short short8;
typedef __attribute__((ext_vector_type(4))) float f32x4;

__device__ inline unsigned short f2bf(float f) {
  union { float f; unsigned u; } v; v.f = f;
  unsigned r = (v.u + 0x7FFFu + ((v.u >> 16) & 1u)) >> 16;
  return (unsigned short)r;
}

// ---------------- Kernel 1: bf16 MFMA proj GEMM + (optional) attrs->bf16 convert.
// C layout (bf16): C[node][half*256 + n64blk + c*4 + t] where h = n64blk + t*16 + c.
// half 0 = x@W_src, half 1 = x@W_dst + b_edge (bias folded here).
__global__ __launch_bounds__(256) void proj_mfma(
    const float* __restrict__ x, const float* __restrict__ We,
    const float* __restrict__ be, unsigned short* __restrict__ C,
    float* __restrict__ partial, const float* __restrict__ attrs,
    unsigned short* __restrict__ attrs_bf) {
  const int tid = threadIdx.x;
  if (blockIdx.x >= PROJ_BLOCKS) {
    // convert attrs fp32 -> bf16 (only launched when ws has room)
    const int nt = CONV_BLOCKS * 256;
    const int total4 = 4 * N_EDGES * 16 / 4;
    for (int i = (blockIdx.x - PROJ_BLOCKS) * 256 + tid; i < total4; i += nt) {
      float4 v = ((const float4*)attrs)[i];
      ushort4 o;
      o.x = f2bf(v.x); o.y = f2bf(v.y); o.z = f2bf(v.z); o.w = f2bf(v.w);
      ((ushort4*)attrs_bf)[i] = o;
    }
    return;
  }
  if (blockIdx.x == 0) {
    for (int i = tid; i < 4 * HIDDEN; i += 256) partial[i] = 0.f;
  }
  const int bm = blockIdx.x >> 2;
  const int bn = blockIdx.x & 3;
  const int row0 = bm * 128;
  const int col0 = bn * 128;          // 0,128,256,384
  const int half = col0 >> 8;         // 0: W_src, 1: W_dst
  const int ncol0 = col0 & 255;       // 0 or 128 within half
  const int lane = tid & 63, wave = tid >> 6;
  const int q = lane >> 4, c = lane & 15;
  const int wm = wave >> 1, wn = wave & 1;

  __shared__ unsigned short As[128][32];  // [m][k]
  __shared__ unsigned short Bs[128][32];  // [n][k] (transposed W)

  f32x4 acc[4][4];
#pragma unroll
  for (int i = 0; i < 4; ++i)
#pragma unroll
    for (int t = 0; t < 4; ++t) acc[i][t] = (f32x4){0.f, 0.f, 0.f, 0.f};

  const int ar = tid >> 1;            // A stage row 0..127
  const int ak = (tid & 1) * 16;      // A stage k 0/16
  const int bk = tid >> 3;            // B stage k 0..31
  const int bn0 = (tid & 7) * 16;     // B stage n 0..112

  for (int k0 = 0; k0 < NODE_DIM; k0 += 32) {
    {  // A: x rows -> bf16 LDS
      const int r = row0 + ar;
      short8 t0, t1;
      if (r < N_NODES) {
        const float4* src = (const float4*)&x[(size_t)r * NODE_DIM + k0 + ak];
        float4 f0 = src[0], f1 = src[1], f2 = src[2], f3 = src[3];
        t0[0]=f2bf(f0.x); t0[1]=f2bf(f0.y); t0[2]=f2bf(f0.z); t0[3]=f2bf(f0.w);
        t0[4]=f2bf(f1.x); t0[5]=f2bf(f1.y); t0[6]=f2bf(f1.z); t0[7]=f2bf(f1.w);
        t1[0]=f2bf(f2.x); t1[1]=f2bf(f2.y); t1[2]=f2bf(f2.z); t1[3]=f2bf(f2.w);
        t1[4]=f2bf(f3.x); t1[5]=f2bf(f3.y); t1[6]=f2bf(f3.z); t1[7]=f2bf(f3.w);
      } else {
#pragma unroll
        for (int j = 0; j < 8; ++j) { t0[j] = 0; t1[j] = 0; }
      }
      *(short8*)&As[ar][ak] = t0;
      *(short8*)&As[ar][ak + 8] = t1;
    }
    {  // B: We rows -> transposed bf16 LDS
      const float4* src = (const float4*)&We[(size_t)(half * 256 + k0 + bk) * HIDDEN + ncol0 + bn0];
#pragma unroll
      for (int v = 0; v < 4; ++v) {
        float4 f = src[v];
        Bs[bn0 + v * 4 + 0][bk] = f2bf(f.x);
        Bs[bn0 + v * 4 + 1][bk] = f2bf(f.y);
        Bs[bn0 + v * 4 + 2][bk] = f2bf(f.z);
        Bs[bn0 + v * 4 + 3][bk] = f2bf(f.w);
      }
    }
    __syncthreads();
    short8 Af[4], Bf[4];
#pragma unroll
    for (int i = 0; i < 4; ++i) Af[i] = *(const short8*)&As[wm * 64 + i * 16 + c][q * 8];
#pragma unroll
    for (int t = 0; t < 4; ++t) Bf[t] = *(const short8*)&Bs[wn * 64 + t * 16 + c][q * 8];
#pragma unroll
    for (int i = 0; i < 4; ++i)
#pragma unroll
      for (int t = 0; t < 4; ++t)
        acc[i][t] = __builtin_amdgcn_mfma_f32_16x16x32_bf16(Af[i], Bf[t], acc[i][t], 0, 0, 0);
    __syncthreads();
  }

  float biasv[4] = {0.f, 0.f, 0.f, 0.f};
  const int nbase = ncol0 + wn * 64;
  if (half) {
#pragma unroll
    for (int t = 0; t < 4; ++t) biasv[t] = be[nbase + t * 16 + c];
  }
#pragma unroll
  for (int i = 0; i < 4; ++i) {
#pragma unroll
    for (int r = 0; r < 4; ++r) {
      const int node = row0 + wm * 64 + i * 16 + q * 4 + r;
      if (node < N_NODES) {
        ushort4 o;
        o.x = f2bf(acc[i][0][r] + biasv[0]);
        o.y = f2bf(acc[i][1][r] + biasv[1]);
        o.z = f2bf(acc[i][2][r] + biasv[2]);
        o.w = f2bf(acc[i][3][r] + biasv[3]);
        *(ushort4*)&C[(size_t)node * 512 + half * 256 + nbase + c * 4] = o;
      }
    }
  }
}

// ---------------- Kernel 2: MFMA fused gather + attr-GEMM + relu + mean.
// Base gather from permuted bf16 C: per edge-row one uint2 (4 h-values).
template <bool PRE>
__global__ __launch_bounds__(256) void edge_mfma(
    const unsigned short* __restrict__ C, const int* __restrict__ ei,
    const float* __restrict__ attrs_f, const unsigned short* __restrict__ attrs_b,
    const float* __restrict__ We, float* __restrict__ partial) {
  const int tid = threadIdx.x;
  const int lane = tid & 63, wave = tid >> 6;
  const int q = lane >> 4, c = lane & 15;
  const int hb = wave * 64;

  short8 Bf[4];
#pragma unroll
  for (int t = 0; t < 4; ++t) {
    short8 bf;
#pragma unroll
    for (int j = 0; j < 8; ++j) {
      int k = q * 8 + j;
      float w = (k < 16) ? We[(size_t)(512 + k) * HIDDEN + hb + t * 16 + c] : 0.0f;
      bf[j] = (short)f2bf(w);
    }
    Bf[t] = bf;
  }

  f32x4 acc4[4][4];  // [b][t]
#pragma unroll
  for (int b = 0; b < 4; ++b)
#pragma unroll
    for (int t = 0; t < 4; ++t) acc4[b][t] = (f32x4){0.f, 0.f, 0.f, 0.f};

  const f32x4 zero4 = {0.f, 0.f, 0.f, 0.f};
  const int ngroups = N_EDGES / 16;
  for (int g = blockIdx.x; g < ngroups; g += gridDim.x) {
    const int e0 = g * 16;
    const int4 ns4 = *(const int4*)&ei[e0 + q * 4];
    const int4 nd4 = *(const int4*)&ei[N_EDGES + e0 + q * 4];

    short8 Af[4];
    if (PRE) {
      if (q < 2) {
#pragma unroll
        for (int b = 0; b < 4; ++b)
          Af[b] = *(const short8*)&attrs_b[((size_t)b * N_EDGES + e0 + c) * 16 + q * 8];
      } else {
        short8 z;
#pragma unroll
        for (int j = 0; j < 8; ++j) z[j] = 0;
#pragma unroll
        for (int b = 0; b < 4; ++b) Af[b] = z;
      }
    } else {
      if (q < 2) {
#pragma unroll
        for (int b = 0; b < 4; ++b) {
          const size_t off = ((size_t)b * N_EDGES + e0 + c) * 16 + q * 8;
          const float4 a0 = *(const float4*)&attrs_f[off];
          const float4 a1 = *(const float4*)&attrs_f[off + 4];
          short8 af;
          af[0]=f2bf(a0.x); af[1]=f2bf(a0.y); af[2]=f2bf(a0.z); af[3]=f2bf(a0.w);
          af[4]=f2bf(a1.x); af[5]=f2bf(a1.y); af[6]=f2bf(a1.z); af[7]=f2bf(a1.w);
          Af[b] = af;
        }
      } else {
        short8 z;
#pragma unroll
        for (int j = 0; j < 8; ++j) z[j] = 0;
#pragma unroll
        for (int b = 0; b < 4; ++b) Af[b] = z;
      }
    }

    f32x4 base4[4];  // [t], component = row r (bias already folded into dst half)
    {
      const int nn[4] = {ns4.x, ns4.y, ns4.z, ns4.w};
      const int dd[4] = {nd4.x, nd4.y, nd4.z, nd4.w};
#pragma unroll
      for (int r = 0; r < 4; ++r) {
        const uint2 s = *(const uint2*)&C[(size_t)nn[r] * 512 + hb + c * 4];
        const uint2 d = *(const uint2*)&C[(size_t)dd[r] * 512 + 256 + hb + c * 4];
        base4[0][r] = __uint_as_float(s.x << 16) + __uint_as_float(d.x << 16);
        base4[1][r] = __uint_as_float(s.x & 0xFFFF0000u) + __uint_as_float(d.x & 0xFFFF0000u);
        base4[2][r] = __uint_as_float(s.y << 16) + __uint_as_float(d.y << 16);
        base4[3][r] = __uint_as_float(s.y & 0xFFFF0000u) + __uint_as_float(d.y & 0xFFFF0000u);
      }
    }

#pragma unroll
    for (int b = 0; b < 4; ++b) {
#pragma unroll
      for (int t = 0; t < 4; ++t) {
        f32x4 S = __builtin_amdgcn_mfma_f32_16x16x32_bf16(Af[b], Bf[t], zero4, 0, 0, 0);
        f32x4 u = S + base4[t];
        u[0] = fmaxf(u[0], 0.f); u[1] = fmaxf(u[1], 0.f);
        u[2] = fmaxf(u[2], 0.f); u[3] = fmaxf(u[3], 0.f);
        acc4[b][t] += u;
      }
    }
  }

#pragma unroll
  for (int b = 0; b < 4; ++b)
#pragma unroll
    for (int t = 0; t < 4; ++t) {
      float v = acc4[b][t][0] + acc4[b][t][1] + acc4[b][t][2] + acc4[b][t][3];
      v += __shfl_xor(v, 16, 64);
      v += __shfl_xor(v, 32, 64);
      if (q == 0) atomicAdd(&partial[b * HIDDEN + hb + t * 16 + c], v);
    }
}

// ---------------- Kernel 3: out[b,o] = (S[b,:]/E) @ W_graph + b_graph
__global__ __launch_bounds__(256) void graph_out(
    const float* __restrict__ partial, const float* __restrict__ Wg,
    const float* __restrict__ bg, float* __restrict__ out) {
  const int o = blockIdx.x;    // 0..127
  const int hh = threadIdx.x;  // 0..255
  const int lane = hh & 63, wave = hh >> 6;
  const float w = Wg[(size_t)hh * OUT_DIM + o];
  float v[4];
#pragma unroll
  for (int b = 0; b < 4; ++b) v[b] = partial[b * HIDDEN + hh] * w;
#pragma unroll
  for (int off = 32; off >= 1; off >>= 1)
#pragma unroll
    for (int b = 0; b < 4; ++b) v[b] += __shfl_down(v[b], off, 64);
  __shared__ float red[4][4];
  if (lane == 0)
#pragma unroll
    for (int b = 0; b < 4; ++b) red[wave][b] = v[b];
  __syncthreads();
  if (hh < 4) {
    float s = red[0][hh] + red[1][hh] + red[2][hh] + red[3][hh];
    out[hh * OUT_DIM + o] = s * (1.0f / (float)N_EDGES) + bg[o];
  }
}

extern "C" void kernel_launch(void* const* d_in, const int* in_sizes, int n_in,
                              void* d_out, int out_size, void* d_ws, size_t ws_size,
                              hipStream_t stream) {
  const float* x  = (const float*)d_in[0];
  const int*   ei = (const int*)d_in[1];
  const float* ea = (const float*)d_in[2];
  const float* We = (const float*)d_in[3];
  const float* be = (const float*)d_in[4];
  const float* Wg = (const float*)d_in[5];
  const float* bg = (const float*)d_in[6];
  float* out = (float*)d_out;

  const size_t C_bytes = (size_t)N_NODES * 512 * 2;         // 20.48 MB
  const size_t A_bytes = (size_t)4 * N_EDGES * 16 * 2;      // 51.2 MB
  unsigned short* C = (unsigned short*)d_ws;
  const bool pre = ws_size >= C_bytes + A_bytes + 4096;
  unsigned short* attrs_bf = pre ? (unsigned short*)((char*)d_ws + C_bytes) : nullptr;
  float* partial = (float*)((char*)d_ws + (pre ? C_bytes + A_bytes : C_bytes));

  const int grid1 = pre ? PROJ_BLOCKS + CONV_BLOCKS : PROJ_BLOCKS;
  proj_mfma<<<grid1, 256, 0, stream>>>(x, We, be, C, partial, ea, attrs_bf);
  if (pre)
    edge_mfma<true><<<2048, 256, 0, stream>>>(C, ei, nullptr, attrs_bf, We, partial);
  else
    edge_mfma<false><<<2048, 256, 0, stream>>>(C, ei, ea, nullptr, We, partial);
  graph_out<<<128, 256, 0, stream>>>(partial, Wg, bg, out);
}